// Round 2
// baseline (699.035 us; speedup 1.0000x reference)
//
#include <hip/hip_runtime.h>

// CTC batch loss forward DP. B=256 rows, one wave (64 lanes) per row.
// Lane i holds blank-state 2i ("bv") and label-state 2i+1 ("lv") in registers;
// state 128 (final blank) lives in an extra register ("b64") on lane 63.
// All math in log2 space (native v_exp_f32 / v_log_f32); converted by ln2 at the end.

constexpr int B = 256, T = 512, C = 1024, L = 64;
constexpr int P = 8;                    // prefetch depth (timesteps ahead)
#define NEGV (-1e30f)
#define EPSV (1e-7f)
constexpr float LN2F = 0.69314718055994530942f;

// Native transcendentals: v_exp_f32 computes 2^x, v_log_f32 computes log2(x).
__device__ __forceinline__ float fexp2(float x) { return __builtin_amdgcn_exp2f(x); }
__device__ __forceinline__ float flog2(float x) { return __builtin_amdgcn_logf(x); }

__global__ __launch_bounds__(64, 1)
void ctc_loss_kernel(const int* __restrict__ y_true,
                     const float* __restrict__ y_pred,
                     float* __restrict__ out) {
    const int b    = blockIdx.x;
    const int lane = threadIdx.x;                 // 0..63, lane i <-> label slot i
    const float* p = y_pred + (size_t)b * T * C;  // this row's [T, C] slab

    // --- per-row static setup -------------------------------------------------
    int lab = y_true[b * L + lane];
    int cls = (lab < 0) ? (C - 1) : lab;          // -1 padding -> blank class
    unsigned long long m = __ballot(lab != -1);
    int ll = __popcll(m);                         // label length (== 64 here)
    int clsprev = __shfl_up(cls, 1);
    // skip transition allowed into label state i iff non-blank and != label i-1
    const bool allow    = (lane > 0) && (cls != C - 1) && (cls != clsprev);
    const bool lblValid = (lane < ll);            // state 2i+1 < 2*ll+1
    const bool blkValid = (lane <= ll);           // state 2i   < 2*ll+1
    const bool b64Valid = (ll == 64);             // state 128  < 2*ll+1

    // --- t = 0 init -----------------------------------------------------------
    float eb0 = flog2(p[C - 1] + EPSV);
    float el0 = flog2(p[cls]   + EPSV);
    float bv  = (lane == 0)            ? eb0 : NEGV;  // alpha[0]
    float lv  = (lane == 0 && ll >= 1) ? el0 : NEGV;  // alpha[1]
    float b64 = NEGV;                                 // alpha[128]

    // --- prefetch ring: t = 1..P ---------------------------------------------
    float bufL[P], bufB[P];
#pragma unroll
    for (int k = 0; k < P; ++k) {
        size_t off = (size_t)(1 + k) * C;
        bufL[k] = p[off + cls];       // per-lane gather (label classes)
        bufB[k] = p[off + (C - 1)];   // uniform blank
    }

    // --- DP over t = 1..T-1 ---------------------------------------------------
    for (int t0 = 1; t0 < T; t0 += P) {
#pragma unroll
        for (int k = 0; k < P; ++k) {
            int t = t0 + k;
            if (t >= T) break;
            float vl = bufL[k];
            float vb = bufB[k];
            int tp = t + P; if (tp > T - 1) tp = T - 1;   // clamped tail refetch
            size_t off = (size_t)tp * C;
            bufL[k] = p[off + cls];
            bufB[k] = p[off + (C - 1)];

            float el = flog2(vl + EPSV);
            float eb = flog2(vb + EPSV);

            float lprev = __shfl_up(lv, 1);               // alpha[2i-1] from lane i-1
            if (lane == 0) lprev = NEGV;

            // blank state 2i: lse(bv, lprev) + eb   (skip path never allowed)
            float m1 = fmaxf(bv, lprev);
            float nb = m1 + flog2(fexp2(bv - m1) + fexp2(lprev - m1)) + eb;
            nb = blkValid ? nb : NEGV;

            // label state 2i+1: lse(lv, bv, allow ? lprev : NEG) + el
            float p2 = allow ? lprev : NEGV;
            float m2 = fmaxf(fmaxf(lv, bv), p2);
            float nl = m2 + flog2(fexp2(lv - m2) + fexp2(bv - m2) + fexp2(p2 - m2)) + el;
            nl = lblValid ? nl : NEGV;

            // state 128: lse(b64, lv_63) + eb  (computed on every lane; used on 63)
            float m3 = fmaxf(b64, lv);
            float nb64 = m3 + flog2(fexp2(b64 - m3) + fexp2(lv - m3)) + eb;
            nb64 = b64Valid ? nb64 : NEGV;

            bv = nb; lv = nl; b64 = nb64;
        }
    }

    // --- epilogue: loss = -logaddexp(alpha[2ll], alpha[2ll-1]) ---------------
    float a_last = (ll == 64) ? __shfl(b64, 63) : __shfl(bv, ll);
    float a_prev = (ll > 0)   ? __shfl(lv, ll - 1) : NEGV;
    if (lane == 0) {
        float mm = fmaxf(a_last, a_prev);
        float loss = -(LN2F * (mm + flog2(fexp2(a_last - mm) + fexp2(a_prev - mm))));
        out[b] = loss;
    }
}

extern "C" void kernel_launch(void* const* d_in, const int* in_sizes, int n_in,
                              void* d_out, int out_size, void* d_ws, size_t ws_size,
                              hipStream_t stream) {
    const int*   y_true = (const int*)d_in[0];
    const float* y_pred = (const float*)d_in[1];
    float*       out    = (float*)d_out;
    ctc_loss_kernel<<<B, 64, 0, stream>>>(y_true, y_pred, out);
}

// Round 3
// 672.553 us; speedup vs baseline: 1.0394x; 1.0394x over previous
//
#include <hip/hip_runtime.h>

// CTC batch loss, producer/consumer structure.
// One block (16 waves, 1024 thr) per batch row. Per 128-timestep chunk:
//   phase A: all 16 waves gather the 65 needed classes/timestep (64 labels +
//            blank) from y_pred into LDS  (BW-bound, massive MLP)
//   phase B: wave 0 advances the CTC DP 128 steps from LDS, linear-domain fp32
//            with power-of-2 renormalization every 8 steps (exact scaling).
// Lane i of wave 0 holds blank-state 2i (bv) and label-state 2i+1 (lv);
// state 128 tracked in b64 (lane 63's copy is authoritative).

constexpr int B = 256, T = 512, C = 1024, L = 64;
constexpr int BLK   = 1024;          // 16 waves
constexpr int NW    = BLK / 64;      // 16
constexpr int CHUNK = 128;           // timesteps per LDS tile
constexpr int TPW   = CHUNK / NW;    // 8 timesteps gathered per wave
constexpr int STRIDE = 66;           // 64 labels + 1 blank + 1 pad (floats)
#define EPSV (1e-7f)
constexpr float LN2F = 0.69314718055994530942f;

__device__ __forceinline__ float flog2(float x) { return __builtin_amdgcn_logf(x); }

__global__ __launch_bounds__(BLK, 1)
void ctc_loss_kernel(const int* __restrict__ y_true,
                     const float* __restrict__ y_pred,
                     float* __restrict__ out) {
    __shared__ float e_lds[CHUNK * STRIDE];          // 33792 B

    const int b    = blockIdx.x;
    const int tid  = threadIdx.x;
    const int lane = tid & 63;
    const int wave = tid >> 6;
    const float* p = y_pred + (size_t)b * T * C;

    // --- labels (every wave keeps its own copy; lane i <-> label slot i) -----
    int lab = y_true[b * L + lane];
    int cls = (lab < 0) ? (C - 1) : lab;
    unsigned long long msk = __ballot(lab != -1);
    int ll = __popcll(msk);                          // label length (64 here)
    int clsprev = __shfl_up(cls, 1);
    const bool allow = (lane > 0) && (cls != C - 1) && (cls != clsprev);

    // --- DP state (wave 0) ----------------------------------------------------
    float bv = 0.f, lv = 0.f, b64 = 0.f;
    float shift = 0.f;                               // cumulative log2 scale

    for (int c = 0; c < T / CHUNK; ++c) {
        const int tbase = c * CHUNK;

        // ===== phase A: gather chunk into LDS (all 16 waves) =================
        {
            const int t0 = tbase + wave * TPW;       // this wave's 8 timesteps
            float r[TPW];
#pragma unroll
            for (int k = 0; k < TPW; ++k)
                r[k] = p[(size_t)(t0 + k) * C + cls];          // label gather
            float vb = 0.f;
            if (lane < TPW)
                vb = p[(size_t)(t0 + lane) * C + (C - 1)];     // blanks
#pragma unroll
            for (int k = 0; k < TPW; ++k)
                e_lds[(t0 - tbase + k) * STRIDE + lane] = r[k] + EPSV;
            if (lane < TPW)
                e_lds[(t0 - tbase + lane) * STRIDE + 64] = vb + EPSV;
        }
        __syncthreads();

        // ===== phase B: DP over this chunk (wave 0 only) =====================
        if (wave == 0) {
            for (int g = 0; g < CHUNK; g += 8) {
                float elr[8], ebr[8];
#pragma unroll
                for (int k = 0; k < 8; ++k) {        // batch LDS reads (MLP)
                    elr[k] = e_lds[(g + k) * STRIDE + lane];
                    ebr[k] = e_lds[(g + k) * STRIDE + 64];
                }
#pragma unroll
                for (int k = 0; k < 8; ++k) {
                    const int t = tbase + g + k;
                    const float el = elr[k], eb = ebr[k];
                    if (t == 0) {
                        bv  = (lane == 0) ? eb : 0.f;            // alpha[0]
                        lv  = (lane == 0 && ll >= 1) ? el : 0.f; // alpha[1]
                        b64 = 0.f;                               // alpha[128]
                    } else {
                        float lprev = __shfl_up(lv, 1);          // alpha[2i-1]
                        if (lane == 0) lprev = 0.f;
                        float nb   = (bv + lprev) * eb;          // state 2i
                        float p2   = allow ? lprev : 0.f;
                        float nl   = (lv + bv + p2) * el;        // state 2i+1
                        float nb64 = (b64 + lv) * eb;            // state 128
                        bv = nb; lv = nl; b64 = nb64;
                    }
                    if ((t & 7) == 7) {              // renormalize (exact 2^k)
                        float mx = fmaxf(fmaxf(bv, lv), b64);
#pragma unroll
                        for (int s = 1; s < 64; s <<= 1)
                            mx = fmaxf(mx, __shfl_xor(mx, s));
                        unsigned u = __float_as_uint(mx);
                        int e = (int)((u >> 23) & 0xFF);
                        int sb = 314 - e;            // target max ~2^60
                        if (sb > 254) sb = 254;      // clamp (avoid inf)
                        if (sb < 1)   sb = 1;
                        float scale = __uint_as_float((unsigned)sb << 23);
                        bv *= scale; lv *= scale; b64 *= scale;
                        shift += (float)(sb - 127);  // stored = true * 2^shift
                    }
                }
            }
        }
        __syncthreads();                             // LDS tile reuse guard
    }

    // --- epilogue: loss = -ln(alpha[2ll] + alpha[2ll-1]) ----------------------
    if (wave == 0) {
        float a_last = (ll == 64) ? __shfl(b64, 63) : __shfl(bv, ll);
        float a_prev = (ll > 0)   ? __shfl(lv, ll - 1) : 0.f;
        if (lane == 0) {
            float s = a_last + a_prev;
            out[b] = -(flog2(s) - shift) * LN2F;
        }
    }
}

extern "C" void kernel_launch(void* const* d_in, const int* in_sizes, int n_in,
                              void* d_out, int out_size, void* d_ws, size_t ws_size,
                              hipStream_t stream) {
    const int*   y_true = (const int*)d_in[0];
    const float* y_pred = (const float*)d_in[1];
    float*       out    = (float*)d_out;
    ctc_loss_kernel<<<B, BLK, 0, stream>>>(y_true, y_pred, out);
}